// Round 1
// baseline (631.580 us; speedup 1.0000x reference)
//
#include <hip/hip_runtime.h>
#include <stdint.h>

// BilinearScorer: out[n,r] = sum_{h,k} pred[n,h] U[h,r,k] args[n,k] + bias1[r,:].args[n,:] + bias2[r]
// n=4096, h=k=512, R=64.  137.4 GFLOP fp32-equivalent.
// Strategy: split-bf16 (hi+lo, 3 MFMA passes) => fp32-class accuracy at bf16 MFMA rate.
// Per role r: GEMM first_r = pred @ U[:,r,:]  (M=4096,N=512,K=512), fused epilogue
// dotting each 128-wide n-slab of first_r with args and atomically accumulating out.

#define HID   512
#define ROLES 64
#define NTOK  4096
#define BM    128
#define BN    128
#define BK    32

typedef __attribute__((ext_vector_type(8))) short bf16x8;  // 8 bf16 = 4 VGPRs (guide §3)
typedef __attribute__((ext_vector_type(4))) float f32x4;

__device__ __forceinline__ unsigned short f2b(float f) {
  union { float f; uint32_t u; } v; v.f = f;
  uint32_t u = v.u + (0x7fffu + ((v.u >> 16) & 1u));   // RNE truncate to bf16
  return (unsigned short)(u >> 16);
}
__device__ __forceinline__ float b2f(unsigned short h) {
  union { uint32_t u; float f; } v; v.u = ((uint32_t)h) << 16;
  return v.f;
}

__device__ __forceinline__ void async16(const void* g, void* l) {
  // global -> LDS direct copy, 16B/lane. LDS dest is wave-uniform base + lane*16.
  __builtin_amdgcn_global_load_lds(
      (const __attribute__((address_space(1))) uint32_t*)g,
      (__attribute__((address_space(3))) uint32_t*)l, 16, 0, 0);
}

// ---- prep: split pred (and layout-preserving) into bf16 hi/lo -------------
__global__ __launch_bounds__(256) void split_pred(const float* __restrict__ in,
                                                  unsigned short* __restrict__ hi,
                                                  unsigned short* __restrict__ lo) {
  const int idx = blockIdx.x * blockDim.x + threadIdx.x;     // NTOK*HID/4 threads
  const float4 v = ((const float4*)in)[idx];
  ushort4 h, l;
  h.x = f2b(v.x); l.x = f2b(v.x - b2f(h.x));
  h.y = f2b(v.y); l.y = f2b(v.y - b2f(h.y));
  h.z = f2b(v.z); l.z = f2b(v.z - b2f(h.z));
  h.w = f2b(v.w); l.w = f2b(v.w - b2f(h.w));
  ((ushort4*)hi)[idx] = h;
  ((ushort4*)lo)[idx] = l;
}

// ---- prep: U[h][r][k] -> Ut_{hi,lo}[r][k][h] (transposed so B-frags are h-contiguous)
__global__ __launch_bounds__(256) void split_u(const float* __restrict__ U,
                                               unsigned short* __restrict__ uh,
                                               unsigned short* __restrict__ ul) {
  __shared__ float tile[64][65];                 // +1 pad breaks bank conflicts
  const int h0 = blockIdx.x * 64, n0 = blockIdx.y * 64, r = blockIdx.z;
  const int t = threadIdx.x;
  const int jc = (t & 15) * 4;
#pragma unroll
  for (int ii = 0; ii < 4; ii++) {
    const int i = ii * 16 + (t >> 4);            // h-row within tile
    const float4 v = *(const float4*)(U + ((size_t)(h0 + i) * ROLES + r) * HID + n0 + jc);
    tile[i][jc + 0] = v.x; tile[i][jc + 1] = v.y;
    tile[i][jc + 2] = v.z; tile[i][jc + 3] = v.w;
  }
  __syncthreads();
  const int j = t >> 2, hc = (t & 3) * 16;       // write row n0+j, 16 h values
  const size_t ob = ((size_t)r * HID + n0 + j) * HID + h0 + hc;
  alignas(16) unsigned short hb[16];
  alignas(16) unsigned short lb[16];
#pragma unroll
  for (int q = 0; q < 16; q++) {
    const float x = tile[hc + q][j];
    const unsigned short h = f2b(x);
    hb[q] = h; lb[q] = f2b(x - b2f(h));
  }
  *(uint4*)(uh + ob)     = *(const uint4*)hb;
  *(uint4*)(uh + ob + 8) = *(const uint4*)(hb + 8);
  *(uint4*)(ul + ob)     = *(const uint4*)lb;
  *(uint4*)(ul + ob + 8) = *(const uint4*)(lb + 8);
}

// ---- out init: out[n,r] = bias2[r] (atomics accumulate on top) ------------
__global__ void init_out_k(float* __restrict__ out, const float* __restrict__ b2) {
  const int idx = blockIdx.x * blockDim.x + threadIdx.x;
  out[idx] = b2[idx & (ROLES - 1)];
}

// ---- main fused GEMM ------------------------------------------------------
__global__ __launch_bounds__(256) void bilinear_mfma(
    const unsigned short* __restrict__ predh, const unsigned short* __restrict__ predl,
    const unsigned short* __restrict__ uth,   const unsigned short* __restrict__ utl,
    const float* __restrict__ args, const float* __restrict__ bias1,
    float* __restrict__ out) {
  __shared__ unsigned short sAh[BM * BK];
  __shared__ unsigned short sAl[BM * BK];
  __shared__ unsigned short sBh[BN * BK];
  __shared__ unsigned short sBl[BN * BK];       // 4 x 8KB = 32KB

  const int nblk = blockIdx.x, mblk = blockIdx.y, r = blockIdx.z;
  const int m0 = mblk * BM, n0 = nblk * BN;
  const int tid  = threadIdx.x;
  const int wave = tid >> 6, lane = tid & 63;
  const int col  = lane & 15, quad = lane >> 4;
  const int wm = (wave & 1) * 64, wn = (wave >> 1) * 64;

  // staging geometry: tile = 128 rows x 32 bf16 (64B/row) = 512 x 16B chunks
  const int c0  = tid;                          // chunk 0..255 (and +256)
  const int i0  = c0 >> 2, ko0 = (c0 & 3) * 8;
  const size_t offA0 = (size_t)(m0 + i0) * HID + ko0;
  const size_t offA1 = offA0 + (size_t)64 * HID;
  const size_t offB0 = ((size_t)r * HID + n0 + i0) * HID + ko0;
  const size_t offB1 = offB0 + (size_t)64 * HID;
  const int ldsOff0 = wave * 512;               // ushort elems; wave-uniform
  const int ldsOff1 = 2048 + wave * 512;

  f32x4 acc[4][4];
#pragma unroll
  for (int a = 0; a < 4; a++)
#pragma unroll
    for (int b = 0; b < 4; b++) acc[a][b] = (f32x4){0.f, 0.f, 0.f, 0.f};

  for (int k0 = 0; k0 < HID; k0 += BK) {
    async16(predh + offA0 + k0, sAh + ldsOff0);
    async16(predh + offA1 + k0, sAh + ldsOff1);
    async16(predl + offA0 + k0, sAl + ldsOff0);
    async16(predl + offA1 + k0, sAl + ldsOff1);
    async16(uth + offB0 + k0, sBh + ldsOff0);
    async16(uth + offB1 + k0, sBh + ldsOff1);
    async16(utl + offB0 + k0, sBl + ldsOff0);
    async16(utl + offB1 + k0, sBl + ldsOff1);
    __syncthreads();                            // drains vmcnt (staging done)

    bf16x8 ah[4], al[4], bh[4], bl[4];
#pragma unroll
    for (int mt = 0; mt < 4; mt++) {
      const int rowA = (wm + mt * 16 + col) * BK + quad * 8;  // A[m=col][k=quad*8+j]
      ah[mt] = *(const bf16x8*)(sAh + rowA);
      al[mt] = *(const bf16x8*)(sAl + rowA);
    }
#pragma unroll
    for (int nt = 0; nt < 4; nt++) {
      const int rowB = (wn + nt * 16 + col) * BK + quad * 8;  // B[n=col][k=quad*8+j]
      bh[nt] = *(const bf16x8*)(sBh + rowB);
      bl[nt] = *(const bf16x8*)(sBl + rowB);
    }
#pragma unroll
    for (int mt = 0; mt < 4; mt++)
#pragma unroll
      for (int nt = 0; nt < 4; nt++) {
        acc[mt][nt] = __builtin_amdgcn_mfma_f32_16x16x32_bf16(ah[mt], bh[nt], acc[mt][nt], 0, 0, 0);
        acc[mt][nt] = __builtin_amdgcn_mfma_f32_16x16x32_bf16(ah[mt], bl[nt], acc[mt][nt], 0, 0, 0);
        acc[mt][nt] = __builtin_amdgcn_mfma_f32_16x16x32_bf16(al[mt], bh[nt], acc[mt][nt], 0, 0, 0);
      }
    __syncthreads();
  }

  // epilogue: partial[m] = sum_n (T[m,n] + bias1[r,n]) * args[m,n], atomic into out
  float b1v[4];
#pragma unroll
  for (int nt = 0; nt < 4; nt++)
    b1v[nt] = bias1[r * HID + n0 + wn + nt * 16 + col];

#pragma unroll
  for (int mt = 0; mt < 4; mt++) {
#pragma unroll
    for (int reg = 0; reg < 4; reg++) {
      const int m = m0 + wm + mt * 16 + quad * 4 + reg;   // C/D row = quad*4+reg (m89)
      const float* arow = args + (size_t)m * HID + n0 + wn + col;
      float s = 0.f;
#pragma unroll
      for (int nt = 0; nt < 4; nt++)
        s += (acc[mt][nt][reg] + b1v[nt]) * arow[nt * 16];
      s += __shfl_xor(s, 1);
      s += __shfl_xor(s, 2);
      s += __shfl_xor(s, 4);
      s += __shfl_xor(s, 8);                    // reduce 16-lane row group
      if (col == 0) atomicAdd(out + (size_t)m * ROLES + r, s);
    }
  }
}

// ---- correctness fallback if workspace is too small (slow, pure fp32) -----
__global__ __launch_bounds__(256) void fallback_k(
    const float* __restrict__ pred, const float* __restrict__ args,
    const float* __restrict__ U, const float* __restrict__ b1,
    const float* __restrict__ b2, float* __restrict__ out) {
  const int idx = blockIdx.x * 256 + threadIdx.x;   // 262144
  const int r = idx >> 12;                          // block-uniform role
  const int n = idx & (NTOK - 1);
  const float* arow = args + (size_t)n * HID;
  const float* prow = pred + (size_t)n * HID;
  float acc = 0.f;
  for (int h = 0; h < HID; h++) {
    const float* urow = U + ((size_t)h * ROLES + r) * HID;
    float s = 0.f;
    for (int k = 0; k < HID; k++) s = fmaf(urow[k], arow[k], s);
    acc = fmaf(prow[h], s, acc);
  }
  float sb = 0.f;
  const float* brow = b1 + (size_t)r * HID;
  for (int k = 0; k < HID; k++) sb = fmaf(brow[k], arow[k], sb);
  out[(size_t)n * ROLES + r] = acc + sb + b2[r];
}

extern "C" void kernel_launch(void* const* d_in, const int* in_sizes, int n_in,
                              void* d_out, int out_size, void* d_ws, size_t ws_size,
                              hipStream_t stream) {
  const float* pred = (const float*)d_in[0];
  const float* args = (const float*)d_in[1];
  const float* U    = (const float*)d_in[2];
  const float* b1   = (const float*)d_in[3];
  const float* b2   = (const float*)d_in[4];
  float* out = (float*)d_out;

  const size_t PRED_ELEMS = (size_t)NTOK * HID;         // 2,097,152
  const size_t U_ELEMS    = (size_t)HID * ROLES * HID;  // 16,777,216
  const size_t WS_NEEDED  = (PRED_ELEMS * 2 + U_ELEMS * 2) * sizeof(unsigned short); // ~72 MiB

  if (ws_size < WS_NEEDED) {
    hipLaunchKernelGGL(fallback_k, dim3((NTOK * ROLES) / 256), dim3(256), 0, stream,
                       pred, args, U, b1, b2, out);
    return;
  }

  unsigned short* predh = (unsigned short*)d_ws;
  unsigned short* predl = predh + PRED_ELEMS;
  unsigned short* uth   = predl + PRED_ELEMS;
  unsigned short* utl   = uth + U_ELEMS;

  hipLaunchKernelGGL(split_pred, dim3((unsigned)(PRED_ELEMS / 4 / 256)), dim3(256), 0, stream,
                     pred, predh, predl);
  hipLaunchKernelGGL(split_u, dim3(HID / 64, HID / 64, ROLES), dim3(256), 0, stream,
                     U, uth, utl);
  hipLaunchKernelGGL(init_out_k, dim3((NTOK * ROLES) / 256), dim3(256), 0, stream, out, b2);
  hipLaunchKernelGGL(bilinear_mfma, dim3(HID / BN, NTOK / BM, ROLES), dim3(256), 0, stream,
                     predh, predl, uth, utl, args, b1, out);
}

// Round 2
// 364.696 us; speedup vs baseline: 1.7318x; 1.7318x over previous
//
#include <hip/hip_runtime.h>
#include <stdint.h>

// BilinearScorer: out[n,r] = sum_{h,k} pred[n,h] U[h,r,k] args[n,k] + bias1[r,:].args[n,:] + bias2[r]
// n=4096, h=k=512, R=64.  137.4 GFLOP fp32-equivalent.
// R2 strategy: single-pass FP16 MFMA (11-bit mantissa => absmax ~0.03, well under the
// >=0.125 threshold established in R1) = 1/3 the MFMA work of R1's split-bf16.
// Plus XOR bank-conflict swizzle on the LDS k-chunk slot (R1: 3.35e7 conflicts, 8-way).

#define HID   512
#define ROLES 64
#define NTOK  4096
#define BM    128
#define BN    128
#define BK    32

typedef __attribute__((ext_vector_type(8))) _Float16 f16x8;  // MFMA A/B operand: 4 VGPRs
typedef __attribute__((ext_vector_type(4))) _Float16 f16x4;
typedef __attribute__((ext_vector_type(4))) float    f32x4;

__device__ __forceinline__ void async16(const void* g, void* l) {
  // global -> LDS direct copy, 16B/lane. LDS dest is wave-uniform base + lane*16;
  // per-lane SOURCE address is free, which is how we implement the store-side swizzle.
  __builtin_amdgcn_global_load_lds(
      (const __attribute__((address_space(1))) uint32_t*)g,
      (__attribute__((address_space(3))) uint32_t*)l, 16, 0, 0);
}

// ---- prep: pred fp32 -> fp16 ----------------------------------------------
__global__ __launch_bounds__(256) void cvt_pred(const float* __restrict__ in,
                                                _Float16* __restrict__ out) {
  const int idx = blockIdx.x * 256 + threadIdx.x;        // NTOK*HID/4 threads
  const float4 v = ((const float4*)in)[idx];
  f16x4 o;
  o[0] = (_Float16)v.x; o[1] = (_Float16)v.y;
  o[2] = (_Float16)v.z; o[3] = (_Float16)v.w;
  ((f16x4*)out)[idx] = o;
}

// ---- prep: U[h][r][k] -> Ut[r][k][h] fp16 (B-frags h-contiguous) ----------
__global__ __launch_bounds__(256) void cvt_u(const float* __restrict__ U,
                                             _Float16* __restrict__ ut) {
  __shared__ float tile[64][65];                 // +1 pad breaks bank conflicts
  const int h0 = blockIdx.x * 64, n0 = blockIdx.y * 64, r = blockIdx.z;
  const int t = threadIdx.x;
  const int jc = (t & 15) * 4;
#pragma unroll
  for (int ii = 0; ii < 4; ii++) {
    const int i = ii * 16 + (t >> 4);            // h-row within tile
    const float4 v = *(const float4*)(U + ((size_t)(h0 + i) * ROLES + r) * HID + n0 + jc);
    tile[i][jc + 0] = v.x; tile[i][jc + 1] = v.y;
    tile[i][jc + 2] = v.z; tile[i][jc + 3] = v.w;
  }
  __syncthreads();
  const int j = t >> 2, hc = (t & 3) * 16;       // write row n0+j, 16 h values
  const size_t ob = ((size_t)r * HID + n0 + j) * HID + h0 + hc;
  alignas(16) _Float16 hb[16];
#pragma unroll
  for (int q = 0; q < 16; q++) hb[q] = (_Float16)tile[hc + q][j];
  *(uint4*)(ut + ob)     = *(const uint4*)hb;
  *(uint4*)(ut + ob + 8) = *(const uint4*)(hb + 8);
}

// ---- out init: out[n,r] = bias2[r] (atomics accumulate on top) ------------
__global__ void init_out_k(float* __restrict__ out, const float* __restrict__ b2) {
  const int idx = blockIdx.x * blockDim.x + threadIdx.x;
  out[idx] = b2[idx & (ROLES - 1)];
}

// ---- main fused GEMM ------------------------------------------------------
__global__ __launch_bounds__(256) void bilinear_mfma(
    const _Float16* __restrict__ predf, const _Float16* __restrict__ utf,
    const float* __restrict__ args, const float* __restrict__ bias1,
    float* __restrict__ out) {
  __shared__ _Float16 sA[BM * BK];               // 8 KB
  __shared__ _Float16 sB[BN * BK];               // 8 KB

  const int nblk = blockIdx.x, mblk = blockIdx.y, r = blockIdx.z;
  const int m0 = mblk * BM, n0 = nblk * BN;
  const int tid  = threadIdx.x;
  const int wave = tid >> 6, lane = tid & 63;
  const int col  = lane & 15, quad = lane >> 4;
  const int wm = (wave & 1) * 64, wn = (wave >> 1) * 64;

  // staging: tile = 128 rows x 32 f16 (64B/row) = 512 x 16B chunks; 2 chunks/thread.
  // XOR swizzle: LDS slot jl of row i holds global k-chunk (jl ^ ((i>>1)&3)).
  const int i0  = tid >> 2;                      // row 0..63 (and +64)
  const int sw  = (i0 >> 1) & 3;                 // same for row i0+64 (64>>1 ≡ 0 mod 4)
  const int ko0 = ((tid & 3) ^ sw) * 8;          // swizzled source k-chunk
  const size_t offA0 = (size_t)(m0 + i0) * HID + ko0;
  const size_t offA1 = offA0 + (size_t)64 * HID;
  const size_t offB0 = ((size_t)r * HID + n0 + i0) * HID + ko0;
  const size_t offB1 = offB0 + (size_t)64 * HID;
  const int ldsOff0 = wave * 512;                // f16 elems; wave-uniform base
  const int ldsOff1 = 2048 + wave * 512;

  // reader slot: row = (wm|wn) + mt*16 + col; ((row>>1)&3) == ((col>>1)&3) since
  // wm/2, 8*mt are ≡0 mod 4.  Uniform across mt/nt.
  const int slot8 = (quad ^ ((col >> 1) & 3)) * 8;

  f32x4 acc[4][4];
#pragma unroll
  for (int a = 0; a < 4; a++)
#pragma unroll
    for (int b = 0; b < 4; b++) acc[a][b] = (f32x4){0.f, 0.f, 0.f, 0.f};

  for (int k0 = 0; k0 < HID; k0 += BK) {
    async16(predf + offA0 + k0, sA + ldsOff0);
    async16(predf + offA1 + k0, sA + ldsOff1);
    async16(utf + offB0 + k0, sB + ldsOff0);
    async16(utf + offB1 + k0, sB + ldsOff1);
    __syncthreads();                             // drains vmcnt (staging done)

    f16x8 a[4], b[4];
#pragma unroll
    for (int mt = 0; mt < 4; mt++)
      a[mt] = *(const f16x8*)(sA + (wm + mt * 16 + col) * BK + slot8);
#pragma unroll
    for (int nt = 0; nt < 4; nt++)
      b[nt] = *(const f16x8*)(sB + (wn + nt * 16 + col) * BK + slot8);

#pragma unroll
    for (int mt = 0; mt < 4; mt++)
#pragma unroll
      for (int nt = 0; nt < 4; nt++)
        acc[mt][nt] = __builtin_amdgcn_mfma_f32_16x16x32_f16(a[mt], b[nt], acc[mt][nt], 0, 0, 0);
    __syncthreads();
  }

  // epilogue: partial[m] = sum_n (T[m,n] + bias1[r,n]) * args[m,n], atomic into out
  float b1v[4];
#pragma unroll
  for (int nt = 0; nt < 4; nt++)
    b1v[nt] = bias1[r * HID + n0 + wn + nt * 16 + col];

#pragma unroll
  for (int mt = 0; mt < 4; mt++) {
#pragma unroll
    for (int reg = 0; reg < 4; reg++) {
      const int m = m0 + wm + mt * 16 + quad * 4 + reg;   // C/D row = quad*4+reg (m89)
      const float* arow = args + (size_t)m * HID + n0 + wn + col;
      float s = 0.f;
#pragma unroll
      for (int nt = 0; nt < 4; nt++)
        s += (acc[mt][nt][reg] + b1v[nt]) * arow[nt * 16];
      s += __shfl_xor(s, 1);
      s += __shfl_xor(s, 2);
      s += __shfl_xor(s, 4);
      s += __shfl_xor(s, 8);                     // reduce 16-lane row group
      if (col == 0) atomicAdd(out + (size_t)m * ROLES + r, s);
    }
  }
}

// ---- correctness fallback if workspace is too small (slow, pure fp32) -----
__global__ __launch_bounds__(256) void fallback_k(
    const float* __restrict__ pred, const float* __restrict__ args,
    const float* __restrict__ U, const float* __restrict__ b1,
    const float* __restrict__ b2, float* __restrict__ out) {
  const int idx = blockIdx.x * 256 + threadIdx.x;   // 262144
  const int r = idx >> 12;                          // block-uniform role
  const int n = idx & (NTOK - 1);
  const float* arow = args + (size_t)n * HID;
  const float* prow = pred + (size_t)n * HID;
  float acc = 0.f;
  for (int h = 0; h < HID; h++) {
    const float* urow = U + ((size_t)h * ROLES + r) * HID;
    float s = 0.f;
    for (int k = 0; k < HID; k++) s = fmaf(urow[k], arow[k], s);
    acc = fmaf(prow[h], s, acc);
  }
  float sb = 0.f;
  const float* brow = b1 + (size_t)r * HID;
  for (int k = 0; k < HID; k++) sb = fmaf(brow[k], arow[k], sb);
  out[(size_t)n * ROLES + r] = acc + sb + b2[r];
}

extern "C" void kernel_launch(void* const* d_in, const int* in_sizes, int n_in,
                              void* d_out, int out_size, void* d_ws, size_t ws_size,
                              hipStream_t stream) {
  const float* pred = (const float*)d_in[0];
  const float* args = (const float*)d_in[1];
  const float* U    = (const float*)d_in[2];
  const float* b1   = (const float*)d_in[3];
  const float* b2   = (const float*)d_in[4];
  float* out = (float*)d_out;

  const size_t PRED_ELEMS = (size_t)NTOK * HID;         // 2,097,152
  const size_t U_ELEMS    = (size_t)HID * ROLES * HID;  // 16,777,216
  const size_t WS_NEEDED  = (PRED_ELEMS + U_ELEMS) * sizeof(_Float16); // ~36 MiB

  if (ws_size < WS_NEEDED) {
    hipLaunchKernelGGL(fallback_k, dim3((NTOK * ROLES) / 256), dim3(256), 0, stream,
                       pred, args, U, b1, b2, out);
    return;
  }

  _Float16* predf = (_Float16*)d_ws;
  _Float16* utf   = predf + PRED_ELEMS;

  hipLaunchKernelGGL(cvt_pred, dim3((unsigned)(PRED_ELEMS / 4 / 256)), dim3(256), 0, stream,
                     pred, predf);
  hipLaunchKernelGGL(cvt_u, dim3(HID / 64, HID / 64, ROLES), dim3(256), 0, stream,
                     U, utf);
  hipLaunchKernelGGL(init_out_k, dim3((NTOK * ROLES) / 256), dim3(256), 0, stream, out, b2);
  hipLaunchKernelGGL(bilinear_mfma, dim3(HID / BN, NTOK / BM, ROLES), dim3(256), 0, stream,
                     predf, utf, args, b1, out);
}